// Round 28
// baseline (91.743 us; speedup 1.0000x reference)
//
#include <hip/hip_runtime.h>

// Problem constants: B=2, N=2048, F_IN=128, H=8, F=32
constexpr int Bv  = 2;
constexpr int Nv  = 2048;
constexpr int FIN = 128;
constexpr int Hn  = 8;
constexpr int Fv  = 32;
constexpr int NROW = Bv * Nv;      // 4096 rows
constexpr int S    = NROW * Hn;    // 32768 floats per PQ array

// ---------------------------------------------------------------------------
// prep v2 (r13 verbatim): 256 blocks x 16 rows; wa + x in LDS; writes
// Pj,Qj,Pi,Qi (pq layout: [Pj | Qj | Pi | Qi], each S floats).
// ---------------------------------------------------------------------------
constexpr int PREP_RPB = 16;

__global__ __launch_bounds__(256) void prep_kernel(
    const float* __restrict__ w, const float* __restrict__ a,
    const float* __restrict__ x, float* __restrict__ pq) {
    __shared__ float wa[2 * FIN * Hn];     // 8 KB
    __shared__ float xs[PREP_RPB][FIN];    // 8 KB
    const int tid  = threadIdx.x;
    const int row0 = blockIdx.x * PREP_RPB;

    for (int e = tid; e < 2 * FIN * Hn; e += 256) {
        const int which = e >> 10;
        const int k     = (e >> 3) & (FIN - 1);
        const int h     = e & (Hn - 1);
        const float* ap = a + which * Fv;
        const float* wp = w + (size_t)k * (Fv * Hn) + h * Fv;
        float s = 0.f;
        #pragma unroll
        for (int f = 0; f < Fv; ++f) s = fmaf(wp[f], ap[f], s);
        wa[e] = s;
    }
    {
        float4* xs4 = (float4*)&xs[0][0];
        const float4* xg = (const float4*)(x + (size_t)row0 * FIN);
        #pragma unroll
        for (int i = tid; i < PREP_RPB * FIN / 4; i += 256) xs4[i] = xg[i];
    }
    __syncthreads();

    const int r    = tid >> 4;
    const int rem  = tid & 15;
    const int h    = rem >> 1;
    const int half = rem & 1;
    const int k0   = half * 64;

    float sj = 0.f, si = 0.f;
    #pragma unroll 8
    for (int k = 0; k < 64; ++k) {
        const int kk = k0 + k;
        const float xv = xs[r][kk];
        sj = fmaf(xv, wa[kk * Hn + h], sj);
        si = fmaf(xv, wa[FIN * Hn + kk * Hn + h], si);
    }
    sj += __shfl_xor(sj, 1);
    si += __shfl_xor(si, 1);

    if (half == 0) {
        const int row = row0 + r;
        const int idx = row * Hn + h;
        pq[idx]         = __expf(sj);
        pq[S + idx]     = __expf(0.2f * sj);
        pq[2 * S + idx] = __expf(si);
        pq[3 * S + idx] = __expf(0.2f * si);
    }
}

// ---------------------------------------------------------------------------
// fused row kernel: ONE WAVE = ONE ROW, norm-v3 prefix + r15 store stream.
// 1024 blocks x 256 threads (4 independent waves/block, ONE block barrier).
//   prefix (cheap, all lanes active): 8 g-loads in flight -> wave-local
//     ballot compaction into private LDS quarter -> dense gather (~2 iters)
//     -> 64-lane butterfly -> fold 1/norm by lane parity.
//   stream: 64 x 1KB contiguous wave-stores (slot s = it*64+lane).
// Saves one kernel boundary (~10 us per r26 decomposition) vs the 3-kernel
// split; avoids r15's idle-lane gather and r11's barrier-chain prefix.
// ---------------------------------------------------------------------------
__global__ __launch_bounds__(256) void row_kernel(
    const float* __restrict__ g, const float* __restrict__ pq,
    float* __restrict__ out) {
    const int tid  = threadIdx.x;
    const int wv   = tid >> 6;
    const int lane = tid & 63;
    const int row  = blockIdx.x * 4 + wv;
    const int b    = row >> 11;

    __shared__ int idxs_all[4][512];       // 8 KB; per-wave private quarter
    int* idxs = idxs_all[wv];

    const float4* __restrict__ g4 = (const float4*)(g + (size_t)row * Nv);
    float4 gv[8];
    #pragma unroll
    for (int r = 0; r < 8; ++r) gv[r] = g4[r * 64 + lane];   // all in flight

    float pi[Hn], qi[Hn];
    #pragma unroll
    for (int h = 0; h < Hn; ++h) {
        pi[h] = pq[2 * S + row * Hn + h];
        qi[h] = pq[3 * S + row * Hn + h];
    }

    const unsigned long long below = (1ull << lane) - 1ull;
    int base = 0;
    #pragma unroll
    for (int r = 0; r < 8; ++r) {
        const int j0 = (r * 64 + lane) * 4;
        const unsigned long long m0 = __ballot(gv[r].x != 0.f);
        const unsigned long long m1 = __ballot(gv[r].y != 0.f);
        const unsigned long long m2 = __ballot(gv[r].z != 0.f);
        const unsigned long long m3 = __ballot(gv[r].w != 0.f);
        int off = base + __popcll(m0 & below) + __popcll(m1 & below)
                       + __popcll(m2 & below) + __popcll(m3 & below);
        if (gv[r].x != 0.f) idxs[off++] = j0;
        if (gv[r].y != 0.f) idxs[off++] = j0 + 1;
        if (gv[r].z != 0.f) idxs[off++] = j0 + 2;
        if (gv[r].w != 0.f) idxs[off++] = j0 + 3;
        base += __popcll(m0) + __popcll(m1) + __popcll(m2) + __popcll(m3);
    }
    const int cnt = base;
    __syncthreads();                       // LDS write->read visibility

    const float4* __restrict__ Pj4 = (const float4*)(pq + (size_t)b * Nv * Hn);
    const float4* __restrict__ Qj4 = (const float4*)(pq + S + (size_t)b * Nv * Hn);

    float acc[Hn];
    #pragma unroll
    for (int h = 0; h < Hn; ++h) acc[h] = 0.f;

    for (int t = lane; t < cnt; t += 64) {   // dense: all lanes active
        const int jj = idxs[t];
        const float4 p0 = Pj4[2 * jj], p1 = Pj4[2 * jj + 1];
        const float4 q0 = Qj4[2 * jj], q1 = Qj4[2 * jj + 1];
        acc[0] += fmaxf(pi[0] * p0.x, qi[0] * q0.x);
        acc[1] += fmaxf(pi[1] * p0.y, qi[1] * q0.y);
        acc[2] += fmaxf(pi[2] * p0.z, qi[2] * q0.z);
        acc[3] += fmaxf(pi[3] * p0.w, qi[3] * q0.w);
        acc[4] += fmaxf(pi[4] * p1.x, qi[4] * q1.x);
        acc[5] += fmaxf(pi[5] * p1.y, qi[5] * q1.y);
        acc[6] += fmaxf(pi[6] * p1.z, qi[6] * q1.z);
        acc[7] += fmaxf(pi[7] * p1.w, qi[7] * q1.w);
    }

    // 64-lane butterfly: all lanes end with row totals
    #pragma unroll
    for (int h = 0; h < Hn; ++h) {
        float v = acc[h];
        #pragma unroll
        for (int off = 32; off > 0; off >>= 1) v += __shfl_xor(v, off);
        acc[h] = v;
    }

    // per-lane head-half fold of 1/norm (static indices)
    const bool odd = (lane & 1) != 0;
    float prv[4], qrv[4];
    #pragma unroll
    for (int c = 0; c < 4; ++c) {
        const float ns = odd ? acc[4 + c] : acc[c];
        const float pv = odd ? pi[4 + c] : pi[c];
        const float qv = odd ? qi[4 + c] : qi[c];
        const float rn = 1.0f / ns;          // norm > 0 (diag of g)
        prv[c] = pv * rn;
        qrv[c] = qv * rn;
    }

    // stream-store the row: slot s = it*64+lane, j=s>>1, heads (s&1)*4..+3
    float4* __restrict__ orow = (float4*)(out + (size_t)row * Nv * Hn);
    #pragma unroll 8
    for (int it = 0; it < 64; ++it) {
        const int s = it * 64 + lane;
        const float4 pj = Pj4[s];
        const float4 qj = Qj4[s];
        float4 o;
        o.x = fmaxf(prv[0] * pj.x, qrv[0] * qj.x);
        o.y = fmaxf(prv[1] * pj.y, qrv[1] * qj.y);
        o.z = fmaxf(prv[2] * pj.z, qrv[2] * qj.z);
        o.w = fmaxf(prv[3] * pj.w, qrv[3] * qj.w);
        orow[s] = o;
    }
}

// ---------------------------------------------------------------------------
extern "C" void kernel_launch(void* const* d_in, const int* in_sizes, int n_in,
                              void* d_out, int out_size, void* d_ws, size_t ws_size,
                              hipStream_t stream) {
    const float* g = (const float*)d_in[0];   // (B,N,N)
    const float* x = (const float*)d_in[1];   // (B,N,F_IN)
    const float* w = (const float*)d_in[2];   // (F_IN, F*H)
    const float* a = (const float*)d_in[3];   // (2F,)

    float* pq  = (float*)d_ws;                // 4*S floats = 512 KB
    float* out = (float*)d_out;               // (B,N,N,H) fp32

    prep_kernel<<<NROW / PREP_RPB, 256, 0, stream>>>(w, a, x, pq);
    row_kernel<<<NROW / 4, 256, 0, stream>>>(g, pq, out);
}

// Round 29
// 80.428 us; speedup vs baseline: 1.1407x; 1.1407x over previous
//
#include <hip/hip_runtime.h>

// Problem constants: B=2, N=2048, F_IN=128, H=8, F=32
constexpr int Bv  = 2;
constexpr int Nv  = 2048;
constexpr int FIN = 128;
constexpr int Hn  = 8;
constexpr int Fv  = 32;
constexpr int NROW = Bv * Nv;      // 4096 rows
constexpr int S    = NROW * Hn;    // 32768 floats per PQ array

// ---------------------------------------------------------------------------
// prep v2 (r13 verbatim): 256 blocks x 16 rows.
// ---------------------------------------------------------------------------
constexpr int PREP_RPB = 16;

__global__ __launch_bounds__(256) void prep_kernel(
    const float* __restrict__ w, const float* __restrict__ a,
    const float* __restrict__ x, float* __restrict__ pq) {
    __shared__ float wa[2 * FIN * Hn];     // 8 KB
    __shared__ float xs[PREP_RPB][FIN];    // 8 KB
    const int tid  = threadIdx.x;
    const int row0 = blockIdx.x * PREP_RPB;

    for (int e = tid; e < 2 * FIN * Hn; e += 256) {
        const int which = e >> 10;
        const int k     = (e >> 3) & (FIN - 1);
        const int h     = e & (Hn - 1);
        const float* ap = a + which * Fv;
        const float* wp = w + (size_t)k * (Fv * Hn) + h * Fv;
        float s = 0.f;
        #pragma unroll
        for (int f = 0; f < Fv; ++f) s = fmaf(wp[f], ap[f], s);
        wa[e] = s;
    }
    {
        float4* xs4 = (float4*)&xs[0][0];
        const float4* xg = (const float4*)(x + (size_t)row0 * FIN);
        #pragma unroll
        for (int i = tid; i < PREP_RPB * FIN / 4; i += 256) xs4[i] = xg[i];
    }
    __syncthreads();

    const int r    = tid >> 4;
    const int rem  = tid & 15;
    const int h    = rem >> 1;
    const int half = rem & 1;
    const int k0   = half * 64;

    float sj = 0.f, si = 0.f;
    #pragma unroll 8
    for (int k = 0; k < 64; ++k) {
        const int kk = k0 + k;
        const float xv = xs[r][kk];
        sj = fmaf(xv, wa[kk * Hn + h], sj);
        si = fmaf(xv, wa[FIN * Hn + kk * Hn + h], si);
    }
    sj += __shfl_xor(sj, 1);
    si += __shfl_xor(si, 1);

    if (half == 0) {
        const int row = row0 + r;
        const int idx = row * Hn + h;
        pq[idx]         = __expf(sj);
        pq[S + idx]     = __expf(0.2f * sj);
        pq[2 * S + idx] = __expf(si);
        pq[3 * S + idx] = __expf(0.2f * si);
    }
}

// ---------------------------------------------------------------------------
// norm v4: same wave-per-row inner structure as r22 (measured 5.4 us), but
// 1024 blocks x 256 threads (4 rows/block) — 4x fewer blocks to dispatch.
// ---------------------------------------------------------------------------
__global__ __launch_bounds__(256) void norm_kernel(
    const float* __restrict__ g, const float* __restrict__ pq,
    float* __restrict__ tbl) {
    const int tid  = threadIdx.x;
    const int wv   = tid >> 6;
    const int lane = tid & 63;
    const int row  = blockIdx.x * 4 + wv;
    const int b    = row >> 11;

    __shared__ int idxs_all[4][512];       // 8 KB; per-wave private quarter
    int* idxs = idxs_all[wv];

    const float4* __restrict__ g4 = (const float4*)(g + (size_t)row * Nv);
    float4 gv[8];
    #pragma unroll
    for (int r = 0; r < 8; ++r) gv[r] = g4[r * 64 + lane];   // all in flight

    float pi[Hn], qi[Hn];
    #pragma unroll
    for (int h = 0; h < Hn; ++h) {
        pi[h] = pq[2 * S + row * Hn + h];
        qi[h] = pq[3 * S + row * Hn + h];
    }

    const unsigned long long below = (1ull << lane) - 1ull;
    int base = 0;
    #pragma unroll
    for (int r = 0; r < 8; ++r) {
        const int j0 = (r * 64 + lane) * 4;
        const unsigned long long m0 = __ballot(gv[r].x != 0.f);
        const unsigned long long m1 = __ballot(gv[r].y != 0.f);
        const unsigned long long m2 = __ballot(gv[r].z != 0.f);
        const unsigned long long m3 = __ballot(gv[r].w != 0.f);
        int off = base + __popcll(m0 & below) + __popcll(m1 & below)
                       + __popcll(m2 & below) + __popcll(m3 & below);
        if (gv[r].x != 0.f) idxs[off++] = j0;
        if (gv[r].y != 0.f) idxs[off++] = j0 + 1;
        if (gv[r].z != 0.f) idxs[off++] = j0 + 2;
        if (gv[r].w != 0.f) idxs[off++] = j0 + 3;
        base += __popcll(m0) + __popcll(m1) + __popcll(m2) + __popcll(m3);
    }
    const int cnt = base;
    __syncthreads();                       // LDS write->read visibility

    const float4* __restrict__ Pj4 = (const float4*)(pq + (size_t)b * Nv * Hn);
    const float4* __restrict__ Qj4 = (const float4*)(pq + S + (size_t)b * Nv * Hn);

    float acc[Hn];
    #pragma unroll
    for (int h = 0; h < Hn; ++h) acc[h] = 0.f;

    for (int t = lane; t < cnt; t += 64) {
        const int jj = idxs[t];
        const float4 p0 = Pj4[2 * jj], p1 = Pj4[2 * jj + 1];
        const float4 q0 = Qj4[2 * jj], q1 = Qj4[2 * jj + 1];
        acc[0] += fmaxf(pi[0] * p0.x, qi[0] * q0.x);
        acc[1] += fmaxf(pi[1] * p0.y, qi[1] * q0.y);
        acc[2] += fmaxf(pi[2] * p0.z, qi[2] * q0.z);
        acc[3] += fmaxf(pi[3] * p0.w, qi[3] * q0.w);
        acc[4] += fmaxf(pi[4] * p1.x, qi[4] * q1.x);
        acc[5] += fmaxf(pi[5] * p1.y, qi[5] * q1.y);
        acc[6] += fmaxf(pi[6] * p1.z, qi[6] * q1.z);
        acc[7] += fmaxf(pi[7] * p1.w, qi[7] * q1.w);
    }

    // 64-lane butterfly: all lanes end with row totals
    #pragma unroll
    for (int h = 0; h < Hn; ++h) {
        float v = acc[h];
        #pragma unroll
        for (int off = 32; off > 0; off >>= 1) v += __shfl_xor(v, off);
        acc[h] = v;
    }

    // lane-predicated writes, all indices static
    #pragma unroll
    for (int h = 0; h < Hn; ++h) {
        if (lane == h) {
            const float rn = 1.0f / acc[h];   // diag guarantees > 0
            tbl[row * 16 + h]     = pi[h] * rn;
            tbl[row * 16 + 8 + h] = qi[h] * rn;
        }
    }
}

// ---------------------------------------------------------------------------
// out v6: r10 inner structure (measured at write roofline, ~37 us marginal),
// but 512 blocks — each block owns one row-group of 8 and loops all 4
// slot-groups (register-cached Pj/Qj per group). 4x fewer blocks.
// ---------------------------------------------------------------------------
constexpr int RPB = 8;      // rows per block
constexpr int SPB = 1024;   // float4 slots per slot-group

__global__ __launch_bounds__(256) void out_kernel(
    const float* __restrict__ pq, const float* __restrict__ tbl,
    float* __restrict__ out) {
    const int rg   = blockIdx.x;          // row group 0..511
    const int row0 = rg * RPB;
    const int b    = row0 >> 11;          // 8 rows never straddle a batch
    const int tid  = threadIdx.x;
    const int hh   = tid & 1;             // head-half (slot parity = tid&1)

    const float4* __restrict__ Pb = (const float4*)(pq + (size_t)b * Nv * Hn);
    const float4* __restrict__ Qb = (const float4*)(pq + S + (size_t)b * Nv * Hn);

    #pragma unroll
    for (int sg = 0; sg < 4; ++sg) {
        float4 pjv[4], qjv[4];
        #pragma unroll
        for (int k = 0; k < 4; ++k) {
            const int s = sg * SPB + k * 256 + tid;
            pjv[k] = Pb[s];
            qjv[k] = Qb[s];
        }
        #pragma unroll
        for (int r = 0; r < RPB; ++r) {
            const int row = row0 + r;
            const float4 prv = *(const float4*)(tbl + row * 16 + hh * 4);
            const float4 qrv = *(const float4*)(tbl + row * 16 + 8 + hh * 4);
            float4* __restrict__ orow = (float4*)(out + (size_t)row * Nv * Hn);
            #pragma unroll
            for (int k = 0; k < 4; ++k) {
                const int s = sg * SPB + k * 256 + tid;
                float4 o;
                o.x = fmaxf(prv.x * pjv[k].x, qrv.x * qjv[k].x);
                o.y = fmaxf(prv.y * pjv[k].y, qrv.y * qjv[k].y);
                o.z = fmaxf(prv.z * pjv[k].z, qrv.z * qjv[k].z);
                o.w = fmaxf(prv.w * pjv[k].w, qrv.w * qjv[k].w);
                orow[s] = o;
            }
        }
    }
}

// ---------------------------------------------------------------------------
extern "C" void kernel_launch(void* const* d_in, const int* in_sizes, int n_in,
                              void* d_out, int out_size, void* d_ws, size_t ws_size,
                              hipStream_t stream) {
    const float* g = (const float*)d_in[0];   // (B,N,N)
    const float* x = (const float*)d_in[1];   // (B,N,F_IN)
    const float* w = (const float*)d_in[2];   // (F_IN, F*H)
    const float* a = (const float*)d_in[3];   // (2F,)

    float* pq  = (float*)d_ws;                // 4*S floats = 512 KB
    float* tbl = pq + 4 * S;                  // 4096*16 floats = 256 KB
    float* out = (float*)d_out;               // (B,N,N,H) fp32

    prep_kernel<<<NROW / PREP_RPB, 256, 0, stream>>>(w, a, x, pq);
    norm_kernel<<<NROW / 4, 256, 0, stream>>>(g, pq, tbl);
    out_kernel<<<NROW / RPB, 256, 0, stream>>>(pq, tbl, out);
}

// Round 30
// 76.593 us; speedup vs baseline: 1.1978x; 1.0501x over previous
//
#include <hip/hip_runtime.h>

// Problem constants: B=2, N=2048, F_IN=128, H=8, F=32
constexpr int Bv  = 2;
constexpr int Nv  = 2048;
constexpr int FIN = 128;
constexpr int Hn  = 8;
constexpr int Fv  = 32;
constexpr int NROW = Bv * Nv;      // 4096 rows
constexpr int S    = NROW * Hn;    // 32768 floats per PQ array

// ---------------------------------------------------------------------------
// prep v2: 256 blocks x 16 rows; wa + x in LDS; (row,h) split across 2
// lanes, shfl_xor combine; writes Pj=exp(sj), Qj=exp(.2sj), Pi, Qi.
// pq layout: [Pj | Qj | Pi | Qi], each S floats.
// ---------------------------------------------------------------------------
constexpr int PREP_RPB = 16;

__global__ __launch_bounds__(256) void prep_kernel(
    const float* __restrict__ w, const float* __restrict__ a,
    const float* __restrict__ x, float* __restrict__ pq) {
    __shared__ float wa[2 * FIN * Hn];     // 8 KB
    __shared__ float xs[PREP_RPB][FIN];    // 8 KB
    const int tid  = threadIdx.x;
    const int row0 = blockIdx.x * PREP_RPB;

    for (int e = tid; e < 2 * FIN * Hn; e += 256) {
        const int which = e >> 10;
        const int k     = (e >> 3) & (FIN - 1);
        const int h     = e & (Hn - 1);
        const float* ap = a + which * Fv;
        const float* wp = w + (size_t)k * (Fv * Hn) + h * Fv;
        float s = 0.f;
        #pragma unroll
        for (int f = 0; f < Fv; ++f) s = fmaf(wp[f], ap[f], s);
        wa[e] = s;
    }
    {
        float4* xs4 = (float4*)&xs[0][0];
        const float4* xg = (const float4*)(x + (size_t)row0 * FIN);
        #pragma unroll
        for (int i = tid; i < PREP_RPB * FIN / 4; i += 256) xs4[i] = xg[i];
    }
    __syncthreads();

    const int r    = tid >> 4;
    const int rem  = tid & 15;
    const int h    = rem >> 1;
    const int half = rem & 1;
    const int k0   = half * 64;

    float sj = 0.f, si = 0.f;
    #pragma unroll 8
    for (int k = 0; k < 64; ++k) {
        const int kk = k0 + k;
        const float xv = xs[r][kk];
        sj = fmaf(xv, wa[kk * Hn + h], sj);
        si = fmaf(xv, wa[FIN * Hn + kk * Hn + h], si);
    }
    sj += __shfl_xor(sj, 1);
    si += __shfl_xor(si, 1);

    if (half == 0) {
        const int row = row0 + r;
        const int idx = row * Hn + h;
        pq[idx]         = __expf(sj);
        pq[S + idx]     = __expf(0.2f * sj);
        pq[2 * S + idx] = __expf(si);
        pq[3 * S + idx] = __expf(0.2f * si);
    }
}

// ---------------------------------------------------------------------------
// norm v3: ONE WAVE (64 threads) = ONE ROW (measured: 5.4 us marginal).
// 8 g float4-loads in flight; wave-local ballot compaction (ascending j);
// gather ~112 L2-resident PQ entries; 64-lane butterfly; predicated write.
// ---------------------------------------------------------------------------
__global__ __launch_bounds__(64) void norm_kernel(
    const float* __restrict__ g, const float* __restrict__ pq,
    float* __restrict__ tbl) {
    const int row  = blockIdx.x;
    const int b    = row >> 11;
    const int lane = threadIdx.x;        // 0..63

    __shared__ int idxs[1024];           // 4 KB; cnt ~112 (mean), <<1024

    const float4* __restrict__ g4 = (const float4*)(g + (size_t)row * Nv);
    float4 gv[8];
    #pragma unroll
    for (int r = 0; r < 8; ++r) gv[r] = g4[r * 64 + lane];   // all in flight

    float pi[Hn], qi[Hn];
    #pragma unroll
    for (int h = 0; h < Hn; ++h) {
        pi[h] = pq[2 * S + row * Hn + h];
        qi[h] = pq[3 * S + row * Hn + h];
    }

    const unsigned long long below = (1ull << lane) - 1ull;
    int base = 0;
    #pragma unroll
    for (int r = 0; r < 8; ++r) {
        const int j0 = (r * 64 + lane) * 4;
        const unsigned long long m0 = __ballot(gv[r].x != 0.f);
        const unsigned long long m1 = __ballot(gv[r].y != 0.f);
        const unsigned long long m2 = __ballot(gv[r].z != 0.f);
        const unsigned long long m3 = __ballot(gv[r].w != 0.f);
        int off = base + __popcll(m0 & below) + __popcll(m1 & below)
                       + __popcll(m2 & below) + __popcll(m3 & below);
        if (gv[r].x != 0.f) idxs[off++] = j0;
        if (gv[r].y != 0.f) idxs[off++] = j0 + 1;
        if (gv[r].z != 0.f) idxs[off++] = j0 + 2;
        if (gv[r].w != 0.f) idxs[off++] = j0 + 3;
        base += __popcll(m0) + __popcll(m1) + __popcll(m2) + __popcll(m3);
    }
    const int cnt = base;
    __syncthreads();                     // 1-wave barrier: LDS visibility only

    const float4* __restrict__ Pj4 = (const float4*)(pq + (size_t)b * Nv * Hn);
    const float4* __restrict__ Qj4 = (const float4*)(pq + S + (size_t)b * Nv * Hn);

    float acc[Hn];
    #pragma unroll
    for (int h = 0; h < Hn; ++h) acc[h] = 0.f;

    for (int t = lane; t < cnt; t += 64) {
        const int jj = idxs[t];
        const float4 p0 = Pj4[2 * jj], p1 = Pj4[2 * jj + 1];
        const float4 q0 = Qj4[2 * jj], q1 = Qj4[2 * jj + 1];
        acc[0] += fmaxf(pi[0] * p0.x, qi[0] * q0.x);
        acc[1] += fmaxf(pi[1] * p0.y, qi[1] * q0.y);
        acc[2] += fmaxf(pi[2] * p0.z, qi[2] * q0.z);
        acc[3] += fmaxf(pi[3] * p0.w, qi[3] * q0.w);
        acc[4] += fmaxf(pi[4] * p1.x, qi[4] * q1.x);
        acc[5] += fmaxf(pi[5] * p1.y, qi[5] * q1.y);
        acc[6] += fmaxf(pi[6] * p1.z, qi[6] * q1.z);
        acc[7] += fmaxf(pi[7] * p1.w, qi[7] * q1.w);
    }

    // 64-lane butterfly: all lanes end with row totals
    #pragma unroll
    for (int h = 0; h < Hn; ++h) {
        float v = acc[h];
        #pragma unroll
        for (int off = 32; off > 0; off >>= 1) v += __shfl_xor(v, off);
        acc[h] = v;
    }

    // lane-predicated writes, all indices static
    #pragma unroll
    for (int h = 0; h < Hn; ++h) {
        if (lane == h) {
            const float rn = 1.0f / acc[h];   // diag guarantees > 0
            tbl[row * 16 + h]     = pi[h] * rn;
            tbl[row * 16 + 8 + h] = qi[h] * rn;
        }
    }
}

// ---------------------------------------------------------------------------
// out: reg-cached RPB=8, regular stores — measured AT the write roofline
// (~37 us marginal for 268 MB, r21 duplicate-launch diagnostic).
// ---------------------------------------------------------------------------
constexpr int RPB = 8;      // rows per block
constexpr int SPB = 1024;   // float4 slots per block (of 4096 per row)

__global__ __launch_bounds__(256) void out_kernel(
    const float* __restrict__ pq, const float* __restrict__ tbl,
    float* __restrict__ out) {
    const int bid  = blockIdx.x;          // 0 .. (NROW/RPB)*4 - 1
    const int sg   = bid & 3;             // slot group (4 groups of 1024)
    const int rg   = bid >> 2;            // row group
    const int row0 = rg * RPB;
    const int b    = row0 >> 11;          // 8 rows never straddle a batch
    const int tid  = threadIdx.x;
    const int hh   = tid & 1;             // head-half (slot parity = tid&1)

    const float4* __restrict__ Pb = (const float4*)(pq + (size_t)b * Nv * Hn);
    const float4* __restrict__ Qb = (const float4*)(pq + S + (size_t)b * Nv * Hn);

    float4 pjv[4], qjv[4];
    #pragma unroll
    for (int k = 0; k < 4; ++k) {
        const int s = sg * SPB + k * 256 + tid;
        pjv[k] = Pb[s];
        qjv[k] = Qb[s];
    }

    #pragma unroll
    for (int r = 0; r < RPB; ++r) {
        const int row = row0 + r;
        const float4 prv = *(const float4*)(tbl + row * 16 + hh * 4);
        const float4 qrv = *(const float4*)(tbl + row * 16 + 8 + hh * 4);
        float4* __restrict__ orow = (float4*)(out + (size_t)row * Nv * Hn);
        #pragma unroll
        for (int k = 0; k < 4; ++k) {
            const int s = sg * SPB + k * 256 + tid;
            float4 o;
            o.x = fmaxf(prv.x * pjv[k].x, qrv.x * qjv[k].x);
            o.y = fmaxf(prv.y * pjv[k].y, qrv.y * qjv[k].y);
            o.z = fmaxf(prv.z * pjv[k].z, qrv.z * qjv[k].z);
            o.w = fmaxf(prv.w * pjv[k].w, qrv.w * qjv[k].w);
            orow[s] = o;
        }
    }
}

// ---------------------------------------------------------------------------
extern "C" void kernel_launch(void* const* d_in, const int* in_sizes, int n_in,
                              void* d_out, int out_size, void* d_ws, size_t ws_size,
                              hipStream_t stream) {
    const float* g = (const float*)d_in[0];   // (B,N,N)
    const float* x = (const float*)d_in[1];   // (B,N,F_IN)
    const float* w = (const float*)d_in[2];   // (F_IN, F*H)
    const float* a = (const float*)d_in[3];   // (2F,)

    float* pq  = (float*)d_ws;                // 4*S floats = 512 KB
    float* tbl = pq + 4 * S;                  // 4096*16 floats = 256 KB
    float* out = (float*)d_out;               // (B,N,N,H) fp32

    prep_kernel<<<NROW / PREP_RPB, 256, 0, stream>>>(w, a, x, pq);
    norm_kernel<<<NROW, 64, 0, stream>>>(g, pq, tbl);
    out_kernel<<<(NROW / RPB) * 4, 256, 0, stream>>>(pq, tbl, out);
}